// Round 1
// baseline (8335.080 us; speedup 1.0000x reference)
//
#include <hip/hip_runtime.h>
#include <cstdint>
#include <cstddef>

// ---------------------------------------------------------------------------
// 4-layer GCN autoencoder:
//   L1: relu(Ahat (x  W1) + b1)   256->128  (transform first, propagate 128)
//   L2: relu(Ahat (h1 W2) + b2)   128->64   (transform first, propagate 64)
//   L3: relu((Ahat z) W3 + b3)    64->128   (propagate first, propagate 64)
//   L4:      (Ahat h3) W4 + b4    128->256  (propagate first, propagate 128)
// Ahat = D^-1/2 (A + I) D^-1/2 ; self-loop handled in non-atomic init pass.
// ---------------------------------------------------------------------------

__global__ __launch_bounds__(256) void k_set1(float* __restrict__ deg, int n) {
  int i = blockIdx.x * 256 + threadIdx.x;
  if (i < n) deg[i] = 1.0f;  // self-loop contributes 1 to every in-degree
}

__global__ __launch_bounds__(256) void k_deg(const int* __restrict__ dst,
                                             float* __restrict__ deg, int E) {
  int e = blockIdx.x * 256 + threadIdx.x;
  if (e < E) atomicAdd(&deg[dst[e]], 1.0f);
}

__global__ __launch_bounds__(256) void k_rsqrt(float* __restrict__ d, int n) {
  int i = blockIdx.x * 256 + threadIdx.x;
  if (i < n) d[i] = rsqrtf(d[i]);  // deg >= 1, no clamp needed
}

// out[i,:] = (bias ? bias : 0) + dinv[i]^2 * h[i,:]      (self-loop + bias)
__global__ __launch_bounds__(256) void k_prop_init(const float* __restrict__ h,
                                                   const float* __restrict__ dinv,
                                                   const float* __restrict__ bias,
                                                   float* __restrict__ out,
                                                   int n, int foShift) {
  int t = blockIdx.x * 256 + threadIdx.x;
  int f4Shift = foShift - 2;
  int total = n << f4Shift;
  if (t >= total) return;
  int i  = t >> f4Shift;
  int f4 = t & ((1 << f4Shift) - 1);
  float di = dinv[i];
  float s = di * di;
  float4 v = ((const float4*)h)[t];
  float4 bv = make_float4(0.f, 0.f, 0.f, 0.f);
  if (bias) bv = ((const float4*)bias)[f4];
  float4 o;
  o.x = bv.x + s * v.x;
  o.y = bv.y + s * v.y;
  o.z = bv.z + s * v.z;
  o.w = bv.w + s * v.w;
  ((float4*)out)[t] = o;
}

// out[dst,:] += dinv[src]*dinv[dst] * h[src,:]   (fo/4 threads per edge)
__global__ __launch_bounds__(256) void k_prop_edges(const float* __restrict__ h,
                                                    const int* __restrict__ src,
                                                    const int* __restrict__ dst,
                                                    const float* __restrict__ dinv,
                                                    float* __restrict__ out,
                                                    int E, int foShift) {
  int t = blockIdx.x * 256 + threadIdx.x;
  int tpeShift = foShift - 2;
  int e = t >> tpeShift;
  if (e >= E) return;
  int l = t & ((1 << tpeShift) - 1);
  int s = src[e];
  int d = dst[e];
  float nm = dinv[s] * dinv[d];
  float4 v = *(const float4*)&h[((size_t)s << foShift) + (l << 2)];
  float* o = &out[((size_t)d << foShift) + (l << 2)];
  atomicAdd(o + 0, nm * v.x);
  atomicAdd(o + 1, nm * v.y);
  atomicAdd(o + 2, nm * v.z);
  atomicAdd(o + 3, nm * v.w);
}

__global__ __launch_bounds__(256) void k_relu(float* __restrict__ x, int n4) {
  int t = blockIdx.x * 256 + threadIdx.x;
  if (t >= n4) return;
  float4 v = ((const float4*)x)[t];
  v.x = fmaxf(v.x, 0.f);
  v.y = fmaxf(v.y, 0.f);
  v.z = fmaxf(v.z, 0.f);
  v.w = fmaxf(v.w, 0.f);
  ((float4*)x)[t] = v;
}

// C[N,M] = A[N,K] @ W[K,M] (+bias) (+relu). 64x64 tile, 4x4 per thread.
// As stored transposed (As[k][row]) so both operand reads are float4.
template <int BIAS, int RELU>
__global__ __launch_bounds__(256) void k_gemm(const float* __restrict__ A,
                                              const float* __restrict__ W,
                                              const float* __restrict__ bias,
                                              float* __restrict__ C,
                                              int N, int K, int M) {
  __shared__ float As[64][68];  // [k][row]
  __shared__ float Bs[64][68];  // [k][col]
  const int tid = threadIdx.x;
  const int tx = tid & 15;
  const int ty = tid >> 4;
  const int row0 = blockIdx.x * 64;
  const int col0 = blockIdx.y * 64;

  float acc[4][4] = {};

  for (int kt = 0; kt < K; kt += 64) {
#pragma unroll
    for (int i = 0; i < 4; ++i) {
      int fid = tid + i * 256;       // 0..1023 float4 slots
      int r = fid >> 4;              // 0..63
      int c4 = (fid & 15) << 2;      // 0..60
      // A tile (scatter-transpose into As)
      float4 v = make_float4(0.f, 0.f, 0.f, 0.f);
      int gr = row0 + r;
      if (gr < N) v = *(const float4*)&A[(size_t)gr * K + kt + c4];
      As[c4 + 0][r] = v.x;
      As[c4 + 1][r] = v.y;
      As[c4 + 2][r] = v.z;
      As[c4 + 3][r] = v.w;
      // W tile (rows kt+r, cols col0+c4), coalesced
      float4 w = *(const float4*)&W[(size_t)(kt + r) * M + col0 + c4];
      *(float4*)&Bs[r][c4] = w;
    }
    __syncthreads();

#pragma unroll 8
    for (int k = 0; k < 64; ++k) {
      float4 a4 = *(const float4*)&As[k][ty << 2];
      float4 b4 = *(const float4*)&Bs[k][tx << 2];
      float ar[4] = {a4.x, a4.y, a4.z, a4.w};
      float br[4] = {b4.x, b4.y, b4.z, b4.w};
#pragma unroll
      for (int i = 0; i < 4; ++i)
#pragma unroll
        for (int j = 0; j < 4; ++j) acc[i][j] += ar[i] * br[j];
    }
    __syncthreads();
  }

  float4 bv = make_float4(0.f, 0.f, 0.f, 0.f);
  if (BIAS) bv = *(const float4*)&bias[col0 + (tx << 2)];
#pragma unroll
  for (int i = 0; i < 4; ++i) {
    int gr = row0 + (ty << 2) + i;
    if (gr >= N) continue;
    float4 o;
    o.x = acc[i][0] + bv.x;
    o.y = acc[i][1] + bv.y;
    o.z = acc[i][2] + bv.z;
    o.w = acc[i][3] + bv.w;
    if (RELU) {
      o.x = fmaxf(o.x, 0.f);
      o.y = fmaxf(o.y, 0.f);
      o.z = fmaxf(o.z, 0.f);
      o.w = fmaxf(o.w, 0.f);
    }
    *(float4*)&C[(size_t)gr * M + col0 + (tx << 2)] = o;
  }
}

static inline int cdiv(int a, int b) { return (a + b - 1) / b; }

extern "C" void kernel_launch(void* const* d_in, const int* in_sizes, int n_in,
                              void* d_out, int out_size, void* d_ws, size_t ws_size,
                              hipStream_t stream) {
  const float* x  = (const float*)d_in[0];
  const int*   ei = (const int*)d_in[1];
  const float* W1 = (const float*)d_in[2];
  const float* b1 = (const float*)d_in[3];
  const float* W2 = (const float*)d_in[4];
  const float* b2 = (const float*)d_in[5];
  const float* W3 = (const float*)d_in[6];
  const float* b3 = (const float*)d_in[7];
  const float* W4 = (const float*)d_in[8];
  const float* b4 = (const float*)d_in[9];

  const int N = in_sizes[0] / 256;  // 50000
  const int E = in_sizes[1] / 2;    // 1600000
  const int* src = ei;
  const int* dst = ei + E;

  float* ws   = (float*)d_ws;
  float* dinv = ws;                       // N floats (used as deg first)
  float* A    = ws + 50176;               // N*128 floats
  float* B    = A + 50000 * 128;          // N*128 floats

  float* out = (float*)d_out;

  dim3 blk(256);

  // --- degree / normalization (once) ---
  k_set1<<<cdiv(N, 256), blk, 0, stream>>>(dinv, N);
  k_deg<<<cdiv(E, 256), blk, 0, stream>>>(dst, dinv, E);
  k_rsqrt<<<cdiv(N, 256), blk, 0, stream>>>(dinv, N);

  // --- L1: t = x@W1 ; h1 = relu(prop(t) + b1), width 128 ---
  {
    dim3 g(cdiv(N, 64), 128 / 64);
    k_gemm<0, 0><<<g, blk, 0, stream>>>(x, W1, nullptr, A, N, 256, 128);
    int t4 = N * 128 / 4;
    k_prop_init<<<cdiv(t4, 256), blk, 0, stream>>>(A, dinv, b1, B, N, 7);
    int te = E * (128 / 4);
    k_prop_edges<<<cdiv(te, 256), blk, 0, stream>>>(A, src, dst, dinv, B, E, 7);
    k_relu<<<cdiv(t4, 256), blk, 0, stream>>>(B, t4);
  }
  // --- L2: t = h1@W2 ; z = relu(prop(t) + b2), width 64 ---
  {
    dim3 g(cdiv(N, 64), 64 / 64);
    k_gemm<0, 0><<<g, blk, 0, stream>>>(B, W2, nullptr, A, N, 128, 64);
    int t4 = N * 64 / 4;
    k_prop_init<<<cdiv(t4, 256), blk, 0, stream>>>(A, dinv, b2, B, N, 6);
    int te = E * (64 / 4);
    k_prop_edges<<<cdiv(te, 256), blk, 0, stream>>>(A, src, dst, dinv, B, E, 6);
    k_relu<<<cdiv(t4, 256), blk, 0, stream>>>(B, t4);
  }
  // --- L3: p = prop(z) ; h3 = relu(p@W3 + b3), propagate width 64 ---
  {
    int t4 = N * 64 / 4;
    k_prop_init<<<cdiv(t4, 256), blk, 0, stream>>>(B, dinv, nullptr, A, N, 6);
    int te = E * (64 / 4);
    k_prop_edges<<<cdiv(te, 256), blk, 0, stream>>>(B, src, dst, dinv, A, E, 6);
    dim3 g(cdiv(N, 64), 128 / 64);
    k_gemm<1, 1><<<g, blk, 0, stream>>>(A, W3, b3, B, N, 64, 128);
  }
  // --- L4: p = prop(h3) ; out = p@W4 + b4, propagate width 128 ---
  {
    int t4 = N * 128 / 4;
    k_prop_init<<<cdiv(t4, 256), blk, 0, stream>>>(B, dinv, nullptr, A, N, 7);
    int te = E * (128 / 4);
    k_prop_edges<<<cdiv(te, 256), blk, 0, stream>>>(B, src, dst, dinv, A, E, 7);
    dim3 g(cdiv(N, 64), 256 / 64);
    k_gemm<1, 0><<<g, blk, 0, stream>>>(A, W4, b4, out, N, 128, 256);
  }
}

// Round 2
// 671.408 us; speedup vs baseline: 12.4143x; 12.4143x over previous
//
#include <hip/hip_runtime.h>
#include <cstdint>
#include <cstddef>

// ---------------------------------------------------------------------------
// 4-layer GCN autoencoder, pull-based propagation (CSR built per launch).
//   out[d] = dinv[d] * sum_{s in N(d) u {d}} (dinv[s] * h[s])   (+bias, relu)
// Rows are pre-scaled by dinv in the producer epilogue, so the per-edge
// inner loop is a pure gather-accumulate with no per-edge normalization.
// ---------------------------------------------------------------------------

static inline int cdiv(int a, int b) { return (a + b - 1) / b; }

__global__ __launch_bounds__(256) void k_count(const int* __restrict__ dst,
                                               int* __restrict__ counts, int E) {
  int e = blockIdx.x * 256 + threadIdx.x;
  if (e < E) atomicAdd(&counts[dst[e]], 1);
}

__global__ __launch_bounds__(256) void k_dinv(const int* __restrict__ counts,
                                              float* __restrict__ dinv, int n) {
  int i = blockIdx.x * 256 + threadIdx.x;
  if (i < n) dinv[i] = rsqrtf((float)(counts[i] + 1));  // +1 self loop
}

// hierarchical exclusive scan over counts -> offs (N elements, 196 blocks)
__global__ __launch_bounds__(256) void k_scan1(const int* __restrict__ in,
                                               int* __restrict__ outx,
                                               int* __restrict__ bsums, int n) {
  __shared__ int tmp[256];
  int i = blockIdx.x * 256 + threadIdx.x;
  int v = (i < n) ? in[i] : 0;
  tmp[threadIdx.x] = v;
  __syncthreads();
  int t = v;
  for (int d = 1; d < 256; d <<= 1) {
    int add = (threadIdx.x >= d) ? tmp[threadIdx.x - d] : 0;
    __syncthreads();
    t += add;
    tmp[threadIdx.x] = t;
    __syncthreads();
  }
  if (i < n) outx[i] = t - v;  // exclusive
  if (threadIdx.x == 255) bsums[blockIdx.x] = t;
}

__global__ __launch_bounds__(256) void k_scan2(int* __restrict__ bs, int nb) {
  __shared__ int tmp[256];
  int v = (threadIdx.x < nb) ? bs[threadIdx.x] : 0;
  tmp[threadIdx.x] = v;
  __syncthreads();
  int t = v;
  for (int d = 1; d < 256; d <<= 1) {
    int add = (threadIdx.x >= d) ? tmp[threadIdx.x - d] : 0;
    __syncthreads();
    t += add;
    tmp[threadIdx.x] = t;
    __syncthreads();
  }
  if (threadIdx.x < nb) bs[threadIdx.x] = t - v;  // exclusive
}

__global__ __launch_bounds__(256) void k_scan3(int* __restrict__ offs,
                                               int* __restrict__ cur,
                                               const int* __restrict__ bs, int n) {
  int i = blockIdx.x * 256 + threadIdx.x;
  if (i < n) {
    int o = offs[i] + bs[blockIdx.x];
    offs[i] = o;
    cur[i] = o;
  }
}

__global__ __launch_bounds__(256) void k_scatter(const int* __restrict__ src,
                                                 const int* __restrict__ dst,
                                                 int* __restrict__ cur,
                                                 int* __restrict__ esrc, int E) {
  int e = blockIdx.x * 256 + threadIdx.x;
  if (e < E) {
    int pos = atomicAdd(&cur[dst[e]], 1);
    esrc[pos] = src[e];
  }
}

// Pull propagation: 1 wave per node. WIDE=1 -> width 128 (float2/lane),
// WIDE=0 -> width 64 (float/lane). Epilogue: t=dinv*acc; +bias; relu; *dinv.
template <int WIDE, int BIAS, int RELU, int POST>
__global__ __launch_bounds__(256) void k_pull(const float* __restrict__ h,
                                              const int* __restrict__ esrc,
                                              const int* __restrict__ offs,
                                              const int* __restrict__ counts,
                                              const float* __restrict__ dinv,
                                              const float* __restrict__ bias,
                                              float* __restrict__ out, int n) {
  int node = blockIdx.x * 4 + (threadIdx.x >> 6);
  if (node >= n) return;
  int lane = threadIdx.x & 63;
  const int W = WIDE ? 128 : 64;
  size_t rbase = (size_t)node * W;

  float a0, a1 = 0.f;
  if (WIDE) {
    float2 v = *(const float2*)&h[rbase + lane * 2];
    a0 = v.x; a1 = v.y;            // self loop (row already dinv-scaled)
  } else {
    a0 = h[rbase + lane];
  }

  int beg = offs[node];
  int cnt = counts[node];
  int j = 0;
  for (; j + 4 <= cnt; j += 4) {
    int s0 = esrc[beg + j + 0];
    int s1 = esrc[beg + j + 1];
    int s2 = esrc[beg + j + 2];
    int s3 = esrc[beg + j + 3];
    if (WIDE) {
      float2 v0 = *(const float2*)&h[(size_t)s0 * 128 + lane * 2];
      float2 v1 = *(const float2*)&h[(size_t)s1 * 128 + lane * 2];
      float2 v2 = *(const float2*)&h[(size_t)s2 * 128 + lane * 2];
      float2 v3 = *(const float2*)&h[(size_t)s3 * 128 + lane * 2];
      a0 += (v0.x + v1.x) + (v2.x + v3.x);
      a1 += (v0.y + v1.y) + (v2.y + v3.y);
    } else {
      float v0 = h[(size_t)s0 * 64 + lane];
      float v1 = h[(size_t)s1 * 64 + lane];
      float v2 = h[(size_t)s2 * 64 + lane];
      float v3 = h[(size_t)s3 * 64 + lane];
      a0 += (v0 + v1) + (v2 + v3);
    }
  }
  for (; j < cnt; ++j) {
    int s = esrc[beg + j];
    if (WIDE) {
      float2 v = *(const float2*)&h[(size_t)s * 128 + lane * 2];
      a0 += v.x; a1 += v.y;
    } else {
      a0 += h[(size_t)s * 64 + lane];
    }
  }

  float dv = dinv[node];
  float t0 = dv * a0, t1 = dv * a1;
  if (BIAS) {
    if (WIDE) {
      float2 b = *(const float2*)&bias[lane * 2];
      t0 += b.x; t1 += b.y;
    } else {
      t0 += bias[lane];
    }
  }
  if (RELU) { t0 = fmaxf(t0, 0.f); t1 = fmaxf(t1, 0.f); }
  if (POST) { t0 *= dv; t1 *= dv; }

  if (WIDE) {
    *(float2*)&out[rbase + lane * 2] = make_float2(t0, t1);
  } else {
    out[rbase + lane] = t0;
  }
}

// C[N,M] = A[N,K] @ W[K,M] (+bias) (+relu) (*dinv[row]). 64x64 tile, 4x4/thr.
template <int BIAS, int RELU, int SCALE>
__global__ __launch_bounds__(256) void k_gemm(const float* __restrict__ A,
                                              const float* __restrict__ W,
                                              const float* __restrict__ bias,
                                              const float* __restrict__ dinv,
                                              float* __restrict__ C,
                                              int N, int K, int M) {
  __shared__ float As[64][68];  // [k][row]
  __shared__ float Bs[64][68];  // [k][col]
  const int tid = threadIdx.x;
  const int tx = tid & 15;
  const int ty = tid >> 4;
  const int row0 = blockIdx.x * 64;
  const int col0 = blockIdx.y * 64;

  float acc[4][4] = {};

  for (int kt = 0; kt < K; kt += 64) {
#pragma unroll
    for (int i = 0; i < 4; ++i) {
      int fid = tid + i * 256;
      int r = fid >> 4;
      int c4 = (fid & 15) << 2;
      float4 v = make_float4(0.f, 0.f, 0.f, 0.f);
      int gr = row0 + r;
      if (gr < N) v = *(const float4*)&A[(size_t)gr * K + kt + c4];
      As[c4 + 0][r] = v.x;
      As[c4 + 1][r] = v.y;
      As[c4 + 2][r] = v.z;
      As[c4 + 3][r] = v.w;
      float4 w = *(const float4*)&W[(size_t)(kt + r) * M + col0 + c4];
      *(float4*)&Bs[r][c4] = w;
    }
    __syncthreads();

#pragma unroll 8
    for (int k = 0; k < 64; ++k) {
      float4 a4 = *(const float4*)&As[k][ty << 2];
      float4 b4 = *(const float4*)&Bs[k][tx << 2];
      float ar[4] = {a4.x, a4.y, a4.z, a4.w};
      float br[4] = {b4.x, b4.y, b4.z, b4.w};
#pragma unroll
      for (int i = 0; i < 4; ++i)
#pragma unroll
        for (int j = 0; j < 4; ++j) acc[i][j] += ar[i] * br[j];
    }
    __syncthreads();
  }

  float4 bv = make_float4(0.f, 0.f, 0.f, 0.f);
  if (BIAS) bv = *(const float4*)&bias[col0 + (tx << 2)];
#pragma unroll
  for (int i = 0; i < 4; ++i) {
    int gr = row0 + (ty << 2) + i;
    if (gr >= N) continue;
    float4 o;
    o.x = acc[i][0] + bv.x;
    o.y = acc[i][1] + bv.y;
    o.z = acc[i][2] + bv.z;
    o.w = acc[i][3] + bv.w;
    if (RELU) {
      o.x = fmaxf(o.x, 0.f);
      o.y = fmaxf(o.y, 0.f);
      o.z = fmaxf(o.z, 0.f);
      o.w = fmaxf(o.w, 0.f);
    }
    if (SCALE) {
      float dv = dinv[gr];
      o.x *= dv; o.y *= dv; o.z *= dv; o.w *= dv;
    }
    *(float4*)&C[(size_t)gr * M + col0 + (tx << 2)] = o;
  }
}

extern "C" void kernel_launch(void* const* d_in, const int* in_sizes, int n_in,
                              void* d_out, int out_size, void* d_ws, size_t ws_size,
                              hipStream_t stream) {
  const float* x  = (const float*)d_in[0];
  const int*   ei = (const int*)d_in[1];
  const float* W1 = (const float*)d_in[2];
  const float* b1 = (const float*)d_in[3];
  const float* W2 = (const float*)d_in[4];
  const float* b2 = (const float*)d_in[5];
  const float* W3 = (const float*)d_in[6];
  const float* b3 = (const float*)d_in[7];
  const float* W4 = (const float*)d_in[8];
  const float* b4 = (const float*)d_in[9];

  const int N = in_sizes[0] / 256;  // 50000
  const int E = in_sizes[1] / 2;    // 1600000
  const int* src = ei;
  const int* dst = ei + E;

  const int NP = 50176;  // padded N (multiple of 256)
  int*   counts = (int*)d_ws;
  int*   offs   = counts + NP;
  int*   cur    = offs + NP;
  float* dinv   = (float*)(cur + NP);
  int*   bsums  = (int*)(dinv + NP);
  int*   esrc   = bsums + 256;
  float* A      = (float*)(esrc + E);       // N*128 floats
  float* B      = A + (size_t)N * 128;      // N*128 floats
  float* out    = (float*)d_out;

  dim3 blk(256);
  const int nbN = cdiv(N, 256);  // 196

  // --- CSR build + normalization (per launch; ws not preserved across calls)
  hipMemsetAsync(counts, 0, (size_t)N * sizeof(int), stream);
  k_count<<<cdiv(E, 256), blk, 0, stream>>>(dst, counts, E);
  k_dinv<<<nbN, blk, 0, stream>>>(counts, dinv, N);
  k_scan1<<<nbN, blk, 0, stream>>>(counts, offs, bsums, N);
  k_scan2<<<1, blk, 0, stream>>>(bsums, nbN);
  k_scan3<<<nbN, blk, 0, stream>>>(offs, cur, bsums, N);
  k_scatter<<<cdiv(E, 256), blk, 0, stream>>>(src, dst, cur, esrc, E);

  dim3 gpull(cdiv(N, 4));

  // L1: t1' = dinv o (x @ W1); h1 = relu(dinv*acc + b1)          [A -> B]
  {
    dim3 g(cdiv(N, 64), 128 / 64);
    k_gemm<0, 0, 1><<<g, blk, 0, stream>>>(x, W1, nullptr, dinv, A, N, 256, 128);
    k_pull<1, 1, 1, 0><<<gpull, blk, 0, stream>>>(A, esrc, offs, counts, dinv, b1, B, N);
  }
  // L2: t2' = dinv o (h1 @ W2); z' = dinv*relu(dinv*acc + b2)    [B -> A -> B]
  {
    dim3 g(cdiv(N, 64), 64 / 64);
    k_gemm<0, 0, 1><<<g, blk, 0, stream>>>(B, W2, nullptr, dinv, A, N, 128, 64);
    k_pull<0, 1, 1, 1><<<gpull, blk, 0, stream>>>(A, esrc, offs, counts, dinv, b2, B, N);
  }
  // L3: p3 = dinv*acc(z'); h3' = dinv o relu(p3 @ W3 + b3)       [B -> A -> B]
  {
    k_pull<0, 0, 0, 0><<<gpull, blk, 0, stream>>>(B, esrc, offs, counts, dinv, nullptr, A, N);
    dim3 g(cdiv(N, 64), 128 / 64);
    k_gemm<1, 1, 1><<<g, blk, 0, stream>>>(A, W3, b3, dinv, B, N, 64, 128);
  }
  // L4: p4 = dinv*acc(h3'); out = p4 @ W4 + b4                   [B -> A -> out]
  {
    k_pull<1, 0, 0, 0><<<gpull, blk, 0, stream>>>(B, esrc, offs, counts, dinv, nullptr, A, N);
    dim3 g(cdiv(N, 64), 256 / 64);
    k_gemm<1, 0, 0><<<g, blk, 0, stream>>>(A, W4, b4, nullptr, out, N, 128, 256);
  }
}